// Round 5
// baseline (147.412 us; speedup 1.0000x reference)
//
#include <hip/hip_runtime.h>
#include <math.h>

#define CHANNEL 8
#define KDIM 16
#define DFULL 128
#define MNBR 32
#define ROUT_IT 3
#define TM1 64

typedef __attribute__((ext_vector_type(4))) float f32x4;
typedef __attribute__((ext_vector_type(8))) short short8;
typedef __attribute__((ext_vector_type(8))) _Float16 half8;
typedef __attribute__((ext_vector_type(2))) _Float16 half2v;

// f32 pair -> packed f16 dword (v_cvt_pkrtz_f16_f32, 1 instr)
__device__ inline unsigned pk16(float a, float b) {
  auto r = __builtin_amdgcn_cvt_pkrtz(a, b);
  return __builtin_bit_cast(unsigned, r);
}
// packed-f16 dot2 with f32 accumulate: v_dot2_f32_f16 (1 instr, no unpack)
__device__ inline float fdot2(unsigned a, unsigned b, float c) {
  return __builtin_amdgcn_fdot2(__builtin_bit_cast(half2v, a),
                                __builtin_bit_cast(half2v, b), c, false);
}
__device__ inline float h2f_lo(unsigned w) {
  union { ushort u; _Float16 h; } v; v.u = (ushort)(w & 0xffffu); return (float)v.h;
}
__device__ inline float h2f_hi(unsigned w) {
  union { ushort u; _Float16 h; } v; v.u = (ushort)(w >> 16); return (float)v.h;
}
// packed f16 helpers (v_pk_fma_f16 / v_pk_add_f16 / v_pk_mul_f16)
__device__ inline half2v h2(unsigned u) { return __builtin_bit_cast(half2v, u); }
__device__ inline unsigned unh(half2v h) { return __builtin_bit_cast(unsigned, h); }
__device__ inline unsigned pkfma16(unsigned a, unsigned b, unsigned c) {
  return unh(__builtin_elementwise_fma(h2(a), h2(b), h2(c)));
}
// DPP reduction step: x + dpp_move<C>(x). 0xB1=quad_perm xor1, 0x4E=quad_perm
// xor2, 0x141=row_half_mirror (xor4 once lower 2 bits uniform).
template <int C>
__device__ inline float dppadd(float x) {
  int m = __builtin_amdgcn_update_dpp(0, __builtin_bit_cast(int, x), C, 0xF, 0xF, true);
  return x + __builtin_bit_cast(float, m);
}

union H8 { unsigned u[4]; short8 v; };
__device__ inline short8 pack8h(float4 a, float4 b) {  // 8 f32 -> 8 f16 (RTZ)
  H8 r;
  r.u[0] = pk16(a.x, a.y); r.u[1] = pk16(a.z, a.w);
  r.u[2] = pk16(b.x, b.y); r.u[3] = pk16(b.z, b.w);
  return r.v;
}

// ---------------------------------------------------------------------------
// K1: z16[r] = f16(normalize_per_capsule(relu(x @ W^T + b))), row n = 0.
// Round-5: wpack kernel MERGED in — each block packs W (f32, 64 KB, L2-hot)
// directly into LDS fragment order (same layout the MFMA loop reads). Removes
// one kernel launch + the wpk global round-trip.
// ---------------------------------------------------------------------------
__global__ __launch_bounds__(256) void fc_mfma_kernel(
    const float* __restrict__ x, const float* __restrict__ W,
    const float* __restrict__ bias, ushort* __restrict__ z16, int n) {
  __shared__ __align__(16) float smem[TM1 * 132];  // 33792 B >= 32768 B W stage

  const int t = threadIdx.x, lane = t & 63, w = t >> 6;

  // pack W -> LDS in MFMA B-fragment order: frag f = kk*8+j, lane l=(L,H):
  // lw[f*64+l] = f16(W[j*16+L][kk*32 + H*8 .. +7])
  {
    short8* lw = (short8*)smem;
#pragma unroll
    for (int i = 0; i < 8; ++i) {
      int task = t + i * 256;  // 0..2047
      int f = task >> 6, l = task & 63;
      int kk = f >> 3, j = f & 7, L = l & 15, H = l >> 4;
      const float* src = W + (size_t)(j * 16 + L) * 128 + kk * 32 + H * 8;
      float4 a = *(const float4*)src;
      float4 b = *(const float4*)(src + 4);
      lw[task] = pack8h(a, b);
    }
  }

  const int L = lane & 15, H = lane >> 4;
  const int r0 = blockIdx.x * TM1;
  const int row = r0 + w * 16 + L;
  const bool ok = row < n;
  const float4 z4 = make_float4(0.f, 0.f, 0.f, 0.f);

  const float* xr = x + (size_t)row * DFULL + H * 8;
  short8 af[4];
#pragma unroll
  for (int kk = 0; kk < 4; ++kk) {
    float4 xa = ok ? *(const float4*)(xr + kk * 32) : z4;
    float4 xb = ok ? *(const float4*)(xr + kk * 32 + 4) : z4;
    af[kk] = pack8h(xa, xb);
  }

  f32x4 acc[8];
#pragma unroll
  for (int j = 0; j < 8; ++j) {
    float bv = bias[j * 16 + L];
    acc[j] = (f32x4){bv, bv, bv, bv};
  }
  __syncthreads();  // W fragments staged
  const short8* wf = (const short8*)smem;
#pragma unroll
  for (int j = 0; j < 8; ++j)
#pragma unroll
    for (int kk = 0; kk < 4; ++kk) {
      short8 bfr = wf[(kk * 8 + j) * 64 + lane];
      acc[j] = __builtin_amdgcn_mfma_f32_16x16x32_f16(
          __builtin_bit_cast(half8, af[kk]), __builtin_bit_cast(half8, bfr),
          acc[j], 0, 0, 0);
    }
  __syncthreads();  // all waves done reading W LDS; reuse as ys

  float* ys = smem;
  const int lr = w * 16 + H * 4;
#pragma unroll
  for (int j = 0; j < 8; ++j)
#pragma unroll
    for (int r = 0; r < 4; ++r)
      ys[(lr + r) * 132 + j * 16 + L] = fmaxf(acc[j][r], 0.f);
  __syncthreads();

#pragma unroll
  for (int pass = 0; pass < 2; ++pass) {
    int task = t + pass * 256;
    int rr = task >> 3, cc = task & 7;
    const float4* yr = (const float4*)(ys + rr * 132 + cc * 16);
    float4 a = yr[0], b = yr[1], c4 = yr[2], d4 = yr[3];
    float ss = a.x * a.x;
    ss = fmaf(a.y, a.y, ss); ss = fmaf(a.z, a.z, ss); ss = fmaf(a.w, a.w, ss);
    ss = fmaf(b.x, b.x, ss); ss = fmaf(b.y, b.y, ss); ss = fmaf(b.z, b.z, ss);
    ss = fmaf(b.w, b.w, ss); ss = fmaf(c4.x, c4.x, ss); ss = fmaf(c4.y, c4.y, ss);
    ss = fmaf(c4.z, c4.z, ss); ss = fmaf(c4.w, c4.w, ss); ss = fmaf(d4.x, d4.x, ss);
    ss = fmaf(d4.y, d4.y, ss); ss = fmaf(d4.z, d4.z, ss); ss = fmaf(d4.w, d4.w, ss);
    float sc = 1.f / fmaxf(sqrtf(ss), 1e-12f);
    int grow = r0 + rr;
    if (grow < n) {
      uint4 o0, o1;
      o0.x = pk16(a.x * sc, a.y * sc);  o0.y = pk16(a.z * sc, a.w * sc);
      o0.z = pk16(b.x * sc, b.y * sc);  o0.w = pk16(b.z * sc, b.w * sc);
      o1.x = pk16(c4.x * sc, c4.y * sc); o1.y = pk16(c4.z * sc, c4.w * sc);
      o1.z = pk16(d4.x * sc, d4.y * sc); o1.w = pk16(d4.z * sc, d4.w * sc);
      uint4* dst = (uint4*)(z16 + (size_t)grow * DFULL + cc * 16);
      dst[0] = o0; dst[1] = o1;
    } else if (grow == n) {  // pad row = zeros
      uint4 zz = {0u, 0u, 0u, 0u};
      uint4* dst = (uint4*)(z16 + (size_t)grow * DFULL + cc * 16);
      dst[0] = zz; dst[1] = zz;
    }
  }
}

// ---------------------------------------------------------------------------
// K2: routing — register-resident, zero LDS arrays, zero barriers.
// Round-5 deltas:
//  (1) DEFER-NORM: upk stays the RAW accumulated u; the normalize scale sc is
//      folded into the next p-phase's exp argument (p = <norm(u),r> =
//      sc*<u,r>, exact). Kills 8 pk_mul/iter and — key — lets the next
//      iteration's 32 p-dots issue in parallel with the rsq chain instead of
//      serializing behind it.
//  (2) exp via v_exp_f32 directly: e = exp2(A * sc2), sc2 = sc*log2(e).
//  (3) 32-bit gather offsets (s[base]+v32 addressing, no 64-bit addr math).
// ---------------------------------------------------------------------------
__global__ __launch_bounds__(256, 6) void routing_kernel(
    const ushort* __restrict__ z16, const int* __restrict__ nid,
    float* __restrict__ out, int n) {
  const int t = threadIdx.x;
  const int node = blockIdx.x * 4 + (t >> 6);
  if (node >= n) return;
  const int lane = t & 63;
  const int q = lane >> 3, c = lane & 7;

  // ---- load this lane's 4 neighbor-row channel slices (16 f16 = 32B each)
  int4 ids = *(const int4*)(nid + node * MNBR + 4 * q);
  const char* zb = (const char*)z16;
  const unsigned cb = (unsigned)c * 32u;
  unsigned o0 = ((unsigned)ids.x << 8) + cb;
  unsigned o1 = ((unsigned)ids.y << 8) + cb;
  unsigned o2 = ((unsigned)ids.z << 8) + cb;
  unsigned o3 = ((unsigned)ids.w << 8) + cb;
  uint4 R0a = *(const uint4*)(zb + o0), R0b = *(const uint4*)(zb + o0 + 16);
  uint4 R1a = *(const uint4*)(zb + o1), R1b = *(const uint4*)(zb + o1 + 16);
  uint4 R2a = *(const uint4*)(zb + o2), R2b = *(const uint4*)(zb + o2 + 16);
  uint4 R3a = *(const uint4*)(zb + o3), R3b = *(const uint4*)(zb + o3 + 16);
  unsigned r0[8] = {R0a.x, R0a.y, R0a.z, R0a.w, R0b.x, R0b.y, R0b.z, R0b.w};
  unsigned r1[8] = {R1a.x, R1a.y, R1a.z, R1a.w, R1b.x, R1b.y, R1b.z, R1b.w};
  unsigned r2[8] = {R2a.x, R2a.y, R2a.z, R2a.w, R2b.x, R2b.y, R2b.z, R2b.w};
  unsigned r3[8] = {R3a.x, R3a.y, R3a.z, R3a.w, R3b.x, R3b.y, R3b.z, R3b.w};

  // own row, channel c slice (identical across the 8 q-lanes)
  unsigned ox = ((unsigned)node << 8) + cb;
  uint4 X0 = *(const uint4*)(zb + ox), X1 = *(const uint4*)(zb + ox + 16);
  const unsigned EIGHTH = 0x30003000u;  // packed f16 (0.125, 0.125)
  unsigned upk[8], xk8[8];
  {
    unsigned xpk[8] = {X0.x, X0.y, X0.z, X0.w, X1.x, X1.y, X1.z, X1.w};
#pragma unroll
    for (int i = 0; i < 8; ++i) {
      upk[i] = xpk[i];                        // iter-0 u (already normalized)
      xk8[i] = unh(h2(xpk[i]) * h2(EIGHTH));  // exact (exponent shift)
    }
  }
  float sc2 = 1.442695041f;  // log2(e) * sc; sc = 1 for iter 0

#pragma unroll
  for (int it = 0; it < ROUT_IT; ++it) {
    // ---- p-phase: raw agreement dots; normalize scale folded into exp arg
    float A0 = 0.f, A1 = 0.f, A2 = 0.f, A3 = 0.f;
#pragma unroll
    for (int i = 0; i < 8; ++i) {
      A0 = fdot2(r0[i], upk[i], A0);
      A1 = fdot2(r1[i], upk[i], A1);
      A2 = fdot2(r2[i], upk[i], A2);
      A3 = fdot2(r3[i], upk[i], A3);
    }
    float e0 = __builtin_amdgcn_exp2f(A0 * sc2);
    float e1 = __builtin_amdgcn_exp2f(A1 * sc2);
    float e2 = __builtin_amdgcn_exp2f(A2 * sc2);
    float e3 = __builtin_amdgcn_exp2f(A3 * sc2);
    // softmax denominator over the 8 contiguous c-lanes (same q) via DPP
    float D0 = dppadd<0x141>(dppadd<0x4E>(dppadd<0xB1>(e0)));
    float D1 = dppadd<0x141>(dppadd<0x4E>(dppadd<0xB1>(e1)));
    float D2 = dppadd<0x141>(dppadd<0x4E>(dppadd<0xB1>(e2)));
    float D3 = dppadd<0x141>(dppadd<0x4E>(dppadd<0xB1>(e3)));
    unsigned sp0, sp1, sp2, sp3;
    {
      float s0 = e0 * __builtin_amdgcn_rcpf(D0);
      float s1 = e1 * __builtin_amdgcn_rcpf(D1);
      float s2 = e2 * __builtin_amdgcn_rcpf(D2);
      float s3 = e3 * __builtin_amdgcn_rcpf(D3);
      sp0 = pk16(s0, s0); sp1 = pk16(s1, s1);
      sp2 = pk16(s2, s2); sp3 = pk16(s3, s3);
    }
    // ---- u-phase: weighted sum of own 4 rows, seeded with x/8 (residual
    // distributes across the 8-lane butterfly: 8 * x/8 = x)
    unsigned acc[8];
#pragma unroll
    for (int i = 0; i < 8; ++i) {
      unsigned a = pkfma16(r3[i], sp3, xk8[i]);
      a = pkfma16(r2[i], sp2, a);
      a = pkfma16(r1[i], sp1, a);
      acc[i] = pkfma16(r0[i], sp0, a);
    }
    // ---- butterfly sum over the 8 q-lanes (lane bits 3,4,5)
#pragma unroll
    for (int i = 0; i < 8; ++i) {
      int v = __builtin_amdgcn_ds_swizzle((int)acc[i], 0x201F);  // lane^8
      acc[i] = unh(h2(acc[i]) + h2((unsigned)v));
    }
#pragma unroll
    for (int i = 0; i < 8; ++i) {
      int v = __builtin_amdgcn_ds_swizzle((int)acc[i], 0x401F);  // lane^16
      acc[i] = unh(h2(acc[i]) + h2((unsigned)v));
    }
#pragma unroll
    for (int i = 0; i < 8; ++i) {
      int v = __shfl_xor((int)acc[i], 32);                        // lane^32
      acc[i] = unh(h2(acc[i]) + h2((unsigned)v));
    }

    if (it == ROUT_IT - 1) {
      // lane writes k = 2q, 2q+1 (dword q of acc): static 8->1 select tree
      unsigned a0 = (q & 1) ? acc[1] : acc[0];
      unsigned a1 = (q & 1) ? acc[3] : acc[2];
      unsigned a2 = (q & 1) ? acc[5] : acc[4];
      unsigned a3 = (q & 1) ? acc[7] : acc[6];
      unsigned b0 = (q & 2) ? a1 : a0;
      unsigned b1 = (q & 2) ? a3 : a2;
      unsigned sel = (q & 4) ? b1 : b0;
      float2 st; st.x = h2f_lo(sel); st.y = h2f_hi(sel);
      *(float2*)(out + (size_t)node * DFULL + c * KDIM + 2 * q) = st;
    } else {
      // defer-norm: upk stays RAW; only the scalar scale feeds the next exp.
      // rsq chain now runs in parallel with next iteration's p-dots.
      float ss = 0.f;
#pragma unroll
      for (int i = 0; i < 8; ++i) {
        upk[i] = acc[i];
        ss = fdot2(acc[i], acc[i], ss);
      }
      float sc = __builtin_amdgcn_rsqf(fmaxf(ss, 1e-24f));
      sc2 = sc * 1.442695041f;
    }
  }
}

// ---------------------------------------------------------------------------
extern "C" void kernel_launch(void* const* d_in, const int* in_sizes, int n_in,
                              void* d_out, int out_size, void* d_ws, size_t ws_size,
                              hipStream_t stream) {
  const float* x = (const float*)d_in[0];
  const float* W = (const float*)d_in[1];
  const float* b = (const float*)d_in[2];
  const int* nid = (const int*)d_in[3];
  float* out = (float*)d_out;

  int n = in_sizes[0] / DFULL;            // 50000
  int g1 = (n + 1 + TM1 - 1) / TM1;       // 782 (covers rows 0..n)

  ushort* z16 = (ushort*)d_ws;            // (g1*TM1) x 128 f16 table

  fc_mfma_kernel<<<g1, 256, 0, stream>>>(x, W, b, z16, n);
  routing_kernel<<<(n + 3) / 4, 256, 0, stream>>>(z16, nid, out, n);
}